// Round 1
// baseline (903.568 us; speedup 1.0000x reference)
//
#include <hip/hip_runtime.h>
#include <stdint.h>

#define S_LEN 2048
#define NH    16
#define NB    4
#define DH    64
#define DMODEL 1024
#define NQKV  3072

using bf16x8 = __attribute__((ext_vector_type(8))) __bf16;
using f32x4  = __attribute__((ext_vector_type(4))) float;
using us8    = __attribute__((ext_vector_type(8))) unsigned short;

__device__ __forceinline__ unsigned short f2bf_rne(float f) {
    unsigned u = __builtin_bit_cast(unsigned, f);
    return (unsigned short)((u + 0x7FFFu + ((u >> 16) & 1u)) >> 16);
}

__device__ __forceinline__ bf16x8 ld_bf8(const unsigned short* p) {
    return __builtin_bit_cast(bf16x8, *(const us8*)p);
}

__device__ __forceinline__ f32x4 mfma16(bf16x8 a, bf16x8 b, f32x4 c) {
    return __builtin_amdgcn_mfma_f32_16x16x32_bf16(a, b, c, 0, 0, 0);
}

typedef __attribute__((address_space(1))) void* gp1_t;
typedef __attribute__((address_space(3))) void* lp3_t;

__device__ __forceinline__ void gload_lds16(const void* g, void* l) {
    // async 16B/lane global->LDS; LDS dest is wave-uniform base + lane*16
    __builtin_amdgcn_global_load_lds((gp1_t)(const_cast<void*>(g)), (lp3_t)l, 16, 0, 0);
}

// ---------------- fp32 -> bf16 convert ----------------
__global__ void cvt_bf16(const float* __restrict__ in, unsigned short* __restrict__ out, int n4) {
    int i = blockIdx.x * 256 + threadIdx.x;
    if (i < n4) {
        float4 v = ((const float4*)in)[i];
        ushort4 o;
        o.x = f2bf_rne(v.x); o.y = f2bf_rne(v.y);
        o.z = f2bf_rne(v.z); o.w = f2bf_rne(v.w);
        ((ushort4*)out)[i] = o;
    }
}

// ---------------- 128x128x32 bf16 MFMA GEMM (K = 1024), NT layout ----------------
// C[m][n] = sum_k A[m][k] * W[n][k]  (+ bias[n])
// EPI==0: QKV epilogue -> de-interleave into Qb (prescaled by 0.125), Kb, Vb bf16 [B,H,S,DH]
// EPI==1: fp32 out + bias
template <int EPI>
__global__ __launch_bounds__(256) void gemm128(
    const unsigned short* __restrict__ A,
    const unsigned short* __restrict__ W,
    const float* __restrict__ bias,
    float* __restrict__ outF,
    unsigned short* __restrict__ Qb,
    unsigned short* __restrict__ Kb,
    unsigned short* __restrict__ Vb,
    int nTilesN)
{
    __shared__ __align__(16) unsigned short As[128 * 32];
    __shared__ __align__(16) unsigned short Bs[128 * 32];

    const int bm = blockIdx.x / nTilesN;
    const int bn = blockIdx.x % nTilesN;
    const int tileM = bm * 128, tileN = bn * 128;
    const int tid = threadIdx.x, lane = tid & 63, w = tid >> 6;
    const int m16 = lane & 15, quad = lane >> 4;
    const int wm = w >> 1, wn = w & 1;

    f32x4 acc[4][4] = {};

    // staging: 16B chunks, tile = 128 rows x 32 k (64B/row -> 4 chunks/row)
    const int c0 = w * 64 + lane;
    const int r0 = c0 >> 2, k0 = (c0 & 3) * 8;
    const int c1 = (4 + w) * 64 + lane;
    const int r1 = c1 >> 2, k1 = (c1 & 3) * 8;

    const unsigned short* Ag0 = A + (size_t)(tileM + r0) * 1024 + k0;
    const unsigned short* Ag1 = A + (size_t)(tileM + r1) * 1024 + k1;
    const unsigned short* Bg0 = W + (size_t)(tileN + r0) * 1024 + k0;
    const unsigned short* Bg1 = W + (size_t)(tileN + r1) * 1024 + k1;
    unsigned short* lA0 = &As[w * 512];
    unsigned short* lA1 = &As[(4 + w) * 512];
    unsigned short* lB0 = &Bs[w * 512];
    unsigned short* lB1 = &Bs[(4 + w) * 512];

    for (int kk = 0; kk < 1024; kk += 32) {
        gload_lds16(Ag0 + kk, lA0);
        gload_lds16(Ag1 + kk, lA1);
        gload_lds16(Bg0 + kk, lB0);
        gload_lds16(Bg1 + kk, lB1);
        __syncthreads();

        bf16x8 af[4], bf[4];
#pragma unroll
        for (int i = 0; i < 4; i++)
            af[i] = ld_bf8(&As[(wm * 64 + i * 16 + m16) * 32 + quad * 8]);
#pragma unroll
        for (int j = 0; j < 4; j++)
            bf[j] = ld_bf8(&Bs[(wn * 64 + j * 16 + m16) * 32 + quad * 8]);
#pragma unroll
        for (int i = 0; i < 4; i++)
#pragma unroll
            for (int j = 0; j < 4; j++)
                acc[i][j] = mfma16(af[i], bf[j], acc[i][j]);
        __syncthreads();
    }

    // epilogue: C/D layout col = lane&15, row = quad*4 + reg
#pragma unroll
    for (int i = 0; i < 4; i++) {
        const int mrow = tileM + wm * 64 + i * 16 + quad * 4;
#pragma unroll
        for (int j = 0; j < 4; j++) {
            const int nb0 = tileN + wn * 64 + j * 16;
            const int n = nb0 + m16;
            const float bv = bias[n];
            if (EPI == 0) {
                const int hh = nb0 / 192, rem = nb0 % 192;
                const int t = rem / 64, dbase = rem % 64;
                const int d = dbase + m16;
#pragma unroll
                for (int r = 0; r < 4; r++) {
                    float val = acc[i][j][r] + bv;
                    const int m = mrow + r;
                    const int b_ = m >> 11, s_ = m & 2047;
                    const size_t idx = (((size_t)b_ * NH + hh) * S_LEN + s_) * DH + d;
                    if (t == 0)      Qb[idx] = f2bf_rne(val * 0.125f);
                    else if (t == 1) Kb[idx] = f2bf_rne(val);
                    else             Vb[idx] = f2bf_rne(val);
                }
            } else {
#pragma unroll
                for (int r = 0; r < 4; r++) {
                    const int m = mrow + r;
                    outF[(size_t)m * DMODEL + n] = acc[i][j][r] + bv;
                }
            }
        }
    }
}

// ---------------- V transpose: [B,H,S,DH] -> [B,H,DH,S] ----------------
__global__ __launch_bounds__(256) void vtrans(const unsigned short* __restrict__ Vb,
                                              unsigned short* __restrict__ Vt) {
    const int blk = blockIdx.x;
    const int st = blk & 31, bh = blk >> 5;
    __shared__ unsigned short T[64][65];
    const unsigned short* src = Vb + ((size_t)bh * S_LEN + st * 64) * DH;
    const int tid = threadIdx.x;
    for (int c = tid; c < 512; c += 256) {
        const int s_ = c >> 3, dd = (c & 7) * 8;
        us8 v = *(const us8*)(src + s_ * 64 + dd);
#pragma unroll
        for (int j = 0; j < 8; j++) T[s_][dd + j] = v[j];
    }
    __syncthreads();
    unsigned short* dst = Vt + (size_t)bh * DH * S_LEN + st * 64;
    for (int c = tid; c < 512; c += 256) {
        const int dd = c >> 3, s0 = (c & 7) * 8;
        us8 o;
#pragma unroll
        for (int j = 0; j < 8; j++) o[j] = T[s0 + j][dd];
        *(us8*)(dst + (size_t)dd * S_LEN + s0) = o;
    }
}

// ---------------- fused attention (no-max softmax, bounded logits) ----------------
// block = (b, h, 64 q-rows); wave w handles q rows q0..q0+15
__global__ __launch_bounds__(256) void attn(const unsigned short* __restrict__ Qb,
                                            const unsigned short* __restrict__ Kb,
                                            const unsigned short* __restrict__ Vt,
                                            const float* __restrict__ alibi,
                                            unsigned short* __restrict__ ob) {
    const int blk = blockIdx.x;
    const int b_ = blk & 3;                 // b fastest: 4 consecutive blocks share alibi tile
    const int rest = blk >> 2;
    const int qt = rest & 31, hh = rest >> 5;
    const int tid = threadIdx.x, lane = tid & 63, w = tid >> 6;
    const int m16 = lane & 15, quad = lane >> 4;
    const int q0 = qt * 64 + w * 16;
    const size_t bh = (size_t)b_ * NH + hh;

    const unsigned short* Qp = Qb + (bh * S_LEN + q0) * DH;
    const unsigned short* Kp = Kb + bh * S_LEN * DH;
    const unsigned short* Vp = Vt + bh * DH * S_LEN;
    const float* Ap = alibi + ((size_t)hh * S_LEN + q0) * S_LEN;

    // Q A-fragments, held all kernel (Q pre-scaled by 1/sqrt(DH))
    const bf16x8 qf0 = ld_bf8(Qp + m16 * DH + quad * 8);
    const bf16x8 qf1 = ld_bf8(Qp + m16 * DH + 32 + quad * 8);

    f32x4 oacc[4] = {};
    float lsum[4] = {};

    __shared__ __align__(16) unsigned short Pl[4][16][72];  // per-wave, pad 8 to spread banks

    for (int kc = 0; kc < S_LEN; kc += 64) {
        __syncthreads();  // keep waves in lockstep for K/V L1 reuse
        f32x4 sc[4] = {};
#pragma unroll
        for (int nb = 0; nb < 4; nb++) {
            const unsigned short* kp = Kp + (size_t)(kc + nb * 16 + m16) * DH + quad * 8;
            sc[nb] = mfma16(qf0, ld_bf8(kp), sc[nb]);
            sc[nb] = mfma16(qf1, ld_bf8(kp + 32), sc[nb]);
        }
        // alibi + exp; P (bf16-truncated) to LDS; row-sum uses the SAME truncated values
#pragma unroll
        for (int nb = 0; nb < 4; nb++) {
            const float* ap = Ap + kc + nb * 16 + m16 + (size_t)quad * 4 * S_LEN;
#pragma unroll
            for (int r = 0; r < 4; r++) {
                const float logit = sc[nb][r] + ap[(size_t)r * S_LEN];
                const float p = __expf(logit);
                const unsigned u = __builtin_bit_cast(unsigned, p) & 0xFFFF0000u;
                lsum[r] += __builtin_bit_cast(float, u);
                Pl[w][quad * 4 + r][nb * 16 + m16] = (unsigned short)(u >> 16);
            }
        }
        // P (C-layout) -> A-layout via per-wave LDS round trip; PV
#pragma unroll
        for (int kk = 0; kk < 2; kk++) {
            const bf16x8 pf = ld_bf8(&Pl[w][m16][kk * 32 + quad * 8]);
#pragma unroll
            for (int db = 0; db < 4; db++) {
                const unsigned short* vp =
                    Vp + (size_t)(db * 16 + m16) * S_LEN + kc + kk * 32 + quad * 8;
                oacc[db] = mfma16(pf, ld_bf8(vp), oacc[db]);
            }
        }
    }

    // finalize: reduce row sums across the 16-lane group, normalize, store o [B,S,D] bf16
#pragma unroll
    for (int r = 0; r < 4; r++) {
        float v = lsum[r];
        v += __shfl_xor(v, 1); v += __shfl_xor(v, 2);
        v += __shfl_xor(v, 4); v += __shfl_xor(v, 8);
        lsum[r] = 1.0f / v;
    }
#pragma unroll
    for (int db = 0; db < 4; db++)
#pragma unroll
        for (int r = 0; r < 4; r++) {
            const float val = oacc[db][r] * lsum[r];
            ob[((size_t)b_ * S_LEN + q0 + quad * 4 + r) * DMODEL + hh * DH + db * 16 + m16] =
                f2bf_rne(val);
        }
}

extern "C" void kernel_launch(void* const* d_in, const int* in_sizes, int n_in,
                              void* d_out, int out_size, void* d_ws, size_t ws_size,
                              hipStream_t stream) {
    (void)in_sizes; (void)n_in; (void)out_size; (void)ws_size;
    const float* x      = (const float*)d_in[0];
    const float* alibi  = (const float*)d_in[1];
    const float* w_qkv  = (const float*)d_in[2];
    const float* b_qkv  = (const float*)d_in[3];
    const float* w_o    = (const float*)d_in[4];
    const float* b_o    = (const float*)d_in[5];
    float* out = (float*)d_out;

    char* ws = (char*)d_ws;
    unsigned short* xb    = (unsigned short*)(ws);              // 16.78 MB
    unsigned short* wqkvb = (unsigned short*)(ws + 16777216);   //  6.29 MB
    unsigned short* wob   = (unsigned short*)(ws + 23068672);   //  2.10 MB
    unsigned short* Qb    = (unsigned short*)(ws + 25165824);   // 16.78 MB
    unsigned short* Kb    = (unsigned short*)(ws + 41943040);   // 16.78 MB
    unsigned short* Vb    = (unsigned short*)(ws + 58720256);   // 16.78 MB
    unsigned short* Vt    = (unsigned short*)(ws + 75497472);   // 16.78 MB
    unsigned short* ob    = (unsigned short*)(ws + 92274688);   // 16.78 MB  (total ~104 MB)

    cvt_bf16<<<8192, 256, 0, stream>>>(x, xb, 8388608 / 4);
    cvt_bf16<<<3072, 256, 0, stream>>>(w_qkv, wqkvb, 3145728 / 4);
    cvt_bf16<<<1024, 256, 0, stream>>>(w_o, wob, 1048576 / 4);

    gemm128<0><<<64 * 24, 256, 0, stream>>>(xb, wqkvb, b_qkv, nullptr, Qb, Kb, Vb, 24);
    vtrans<<<2048, 256, 0, stream>>>(Vb, Vt);
    attn<<<2048, 256, 0, stream>>>(Qb, Kb, Vt, alibi, ob);
    gemm128<1><<<64 * 8, 256, 0, stream>>>(ob, wob, b_o, out, nullptr, nullptr, nullptr, 8);
}

// Round 2
// 649.034 us; speedup vs baseline: 1.3922x; 1.3922x over previous
//
#include <hip/hip_runtime.h>
#include <stdint.h>

#define S_LEN 2048
#define NH    16
#define NB    4
#define DH    64
#define DMODEL 1024

using bf16x8 = __attribute__((ext_vector_type(8))) __bf16;
using f32x4  = __attribute__((ext_vector_type(4))) float;
using us8    = __attribute__((ext_vector_type(8))) unsigned short;

__device__ __forceinline__ unsigned short f2bf_rne(float f) {
    unsigned u = __builtin_bit_cast(unsigned, f);
    return (unsigned short)((u + 0x7FFFu + ((u >> 16) & 1u)) >> 16);
}

__device__ __forceinline__ bf16x8 ld_bf8(const unsigned short* p) {
    return __builtin_bit_cast(bf16x8, *(const us8*)p);
}

__device__ __forceinline__ f32x4 mfma16(bf16x8 a, bf16x8 b, f32x4 c) {
    return __builtin_amdgcn_mfma_f32_16x16x32_bf16(a, b, c, 0, 0, 0);
}

__device__ __forceinline__ float fast_exp2(float x) {
#if __has_builtin(__builtin_amdgcn_exp2f)
    return __builtin_amdgcn_exp2f(x);
#else
    return __expf(x * 0.69314718056f);
#endif
}

typedef __attribute__((address_space(1))) void* gp1_t;
typedef __attribute__((address_space(3))) void* lp3_t;

__device__ __forceinline__ void gload_lds16(const void* g, void* l) {
    __builtin_amdgcn_global_load_lds((gp1_t)(const_cast<void*>(g)), (lp3_t)l, 16, 0, 0);
}

// ---------------- fp32 -> bf16 convert ----------------
__global__ void cvt_bf16(const float* __restrict__ in, unsigned short* __restrict__ out, int n4) {
    int i = blockIdx.x * 256 + threadIdx.x;
    if (i < n4) {
        float4 v = ((const float4*)in)[i];
        ushort4 o;
        o.x = f2bf_rne(v.x); o.y = f2bf_rne(v.y);
        o.z = f2bf_rne(v.z); o.w = f2bf_rne(v.w);
        ((ushort4*)out)[i] = o;
    }
}

// ---------------- 128x128x32 bf16 MFMA GEMM (K = 1024), NT layout ----------------
// EPI==0: QKV epilogue -> Qb (prescaled by 0.125*log2e), Kb [B,H,S,DH], Vt [B,H,DH,S]
// EPI==1: fp32 out + bias
template <int EPI>
__global__ __launch_bounds__(256) void gemm128(
    const unsigned short* __restrict__ A,
    const unsigned short* __restrict__ W,
    const float* __restrict__ bias,
    float* __restrict__ outF,
    unsigned short* __restrict__ Qb,
    unsigned short* __restrict__ Kb,
    unsigned short* __restrict__ Vt,
    int nTilesN)
{
    __shared__ __align__(16) unsigned short As[128 * 32];
    __shared__ __align__(16) unsigned short Bs[128 * 32];

    const int bm = blockIdx.x / nTilesN;
    const int bn = blockIdx.x % nTilesN;
    const int tileM = bm * 128, tileN = bn * 128;
    const int tid = threadIdx.x, lane = tid & 63, w = tid >> 6;
    const int m16 = lane & 15, quad = lane >> 4;
    const int wm = w >> 1, wn = w & 1;

    f32x4 acc[4][4] = {};

    const int c0 = w * 64 + lane;
    const int r0 = c0 >> 2, k0 = (c0 & 3) * 8;
    const int c1 = (4 + w) * 64 + lane;
    const int r1 = c1 >> 2, k1 = (c1 & 3) * 8;

    const unsigned short* Ag0 = A + (size_t)(tileM + r0) * 1024 + k0;
    const unsigned short* Ag1 = A + (size_t)(tileM + r1) * 1024 + k1;
    const unsigned short* Bg0 = W + (size_t)(tileN + r0) * 1024 + k0;
    const unsigned short* Bg1 = W + (size_t)(tileN + r1) * 1024 + k1;
    unsigned short* lA0 = &As[w * 512];
    unsigned short* lA1 = &As[(4 + w) * 512];
    unsigned short* lB0 = &Bs[w * 512];
    unsigned short* lB1 = &Bs[(4 + w) * 512];

    for (int kk = 0; kk < 1024; kk += 32) {
        gload_lds16(Ag0 + kk, lA0);
        gload_lds16(Ag1 + kk, lA1);
        gload_lds16(Bg0 + kk, lB0);
        gload_lds16(Bg1 + kk, lB1);
        __syncthreads();

        bf16x8 af[4], bf[4];
#pragma unroll
        for (int i = 0; i < 4; i++)
            af[i] = ld_bf8(&As[(wm * 64 + i * 16 + m16) * 32 + quad * 8]);
#pragma unroll
        for (int j = 0; j < 4; j++)
            bf[j] = ld_bf8(&Bs[(wn * 64 + j * 16 + m16) * 32 + quad * 8]);
#pragma unroll
        for (int i = 0; i < 4; i++)
#pragma unroll
            for (int j = 0; j < 4; j++)
                acc[i][j] = mfma16(af[i], bf[j], acc[i][j]);
        __syncthreads();
    }

    // epilogue: C/D layout col = lane&15, row = quad*4 + reg
#pragma unroll
    for (int i = 0; i < 4; i++) {
        const int mrow = tileM + wm * 64 + i * 16 + quad * 4;
#pragma unroll
        for (int j = 0; j < 4; j++) {
            const int nb0 = tileN + wn * 64 + j * 16;
            const int n = nb0 + m16;
            const float bv = bias[n];
            if (EPI == 0) {
                const int hh = nb0 / 192, rem = nb0 % 192;
                const int t = rem / 64, dbase = rem % 64;
                const int d = dbase + m16;
#pragma unroll
                for (int r = 0; r < 4; r++) {
                    float val = acc[i][j][r] + bv;
                    const int m = mrow + r;
                    const int b_ = m >> 11, s_ = m & 2047;
                    const size_t bh = (size_t)b_ * NH + hh;
                    if (t == 0)
                        Qb[(bh * S_LEN + s_) * DH + d] = f2bf_rne(val * 0.18033688f); // 0.125*log2e
                    else if (t == 1)
                        Kb[(bh * S_LEN + s_) * DH + d] = f2bf_rne(val);
                    else
                        Vt[(bh * DH + d) * S_LEN + s_] = f2bf_rne(val);  // transposed V
                }
            } else {
#pragma unroll
                for (int r = 0; r < 4; r++) {
                    const int m = mrow + r;
                    outF[(size_t)m * DMODEL + n] = acc[i][j][r] + bv;
                }
            }
        }
    }
}

// ---------------- fused attention ----------------
// block = (b, h, 128 q-rows); 4 waves, each handling 32 q-rows (2 x 16-row frags)
// K-chunk = 128 keys staged in LDS (XOR-swizzled), V likewise from Vt [d][s].
// QK uses mfma(K,Q) so each lane holds 4 k-consecutive logits -> float4 alibi load,
// ds_write_b64 P pack. Row-sums via ones-fragment MFMA (lands in O's C-layout rows).
__global__ __launch_bounds__(256, 4) void attn(const unsigned short* __restrict__ Qb,
                                               const unsigned short* __restrict__ Kb,
                                               const unsigned short* __restrict__ Vt,
                                               const float* __restrict__ alibi,
                                               unsigned short* __restrict__ ob) {
    const int blk = blockIdx.x;
    // XCD swizzle: 4 batch-siblings (same alibi strip) at blkIdx stride 8 -> same XCD L2
    const int xcd = blk & 7;
    const int b_  = (blk >> 3) & 3;
    const int hq  = xcd * 32 + (blk >> 5);     // 0..255
    const int hh  = hq >> 4, qt = hq & 15;
    const int tid = threadIdx.x, lane = tid & 63, w = tid >> 6;
    const int m16 = lane & 15, quad = lane >> 4;
    const int q0 = qt * 128;
    const size_t bh = (size_t)b_ * NH + hh;

    const unsigned short* Qp = Qb + (bh * S_LEN) * DH;
    const unsigned short* Kp = Kb + bh * S_LEN * DH;
    const unsigned short* Vp = Vt + bh * DH * S_LEN;

    __shared__ __align__(16) unsigned short Ks[128 * 64];   // [key][d], d-swizzled
    __shared__ __align__(16) unsigned short Vs[64 * 128];   // [d][key], key-swizzled
    __shared__ __align__(16) unsigned int   Pl[4][16 * 20]; // per-wave, stride 20 dwords

    // Q fragments (Q pre-scaled by 0.125*log2e)
    bf16x8 qfrag[2][2];
#pragma unroll
    for (int qf = 0; qf < 2; qf++) {
        const unsigned short* qp = Qp + (size_t)(q0 + w * 32 + qf * 16 + m16) * DH + quad * 8;
        qfrag[qf][0] = ld_bf8(qp);
        qfrag[qf][1] = ld_bf8(qp + 32);
    }
    const float* Apq[2];
#pragma unroll
    for (int qf = 0; qf < 2; qf++)
        Apq[qf] = alibi + ((size_t)hh * S_LEN + q0 + w * 32 + qf * 16 + m16) * S_LEN + quad * 4;

    // staging offsets (global-side XOR swizzle; LDS side is lane-contiguous)
    int offk[4], offv[4];
#pragma unroll
    for (int t = 0; t < 4; t++) {
        const int ck = (w * 4 + t) * 64 + lane;
        const int rk = ck >> 3;
        offk[t] = rk * DH + ((ck & 7) ^ (rk & 7)) * 8;
        const int cv = ck;
        const int dv = cv >> 4;
        offv[t] = dv * S_LEN + ((cv & 15) ^ (dv & 15)) * 8;
    }

    const bf16x8 onesf = __builtin_bit_cast(bf16x8, (us8)(0x3F80u));
    f32x4 oacc[2][4] = {};
    f32x4 ssum[2] = {};
    unsigned int* plw = &Pl[w][0];
    const int sA = m16 & 7;

    for (int kc = 0; kc < S_LEN; kc += 128) {
        __syncthreads();  // previous compute done before overwrite
#pragma unroll
        for (int t = 0; t < 4; t++)
            gload_lds16(Kp + (size_t)kc * DH + offk[t], &Ks[(w * 4 + t) * 512]);
#pragma unroll
        for (int t = 0; t < 4; t++)
            gload_lds16(Vp + kc + offv[t], &Vs[(w * 4 + t) * 512]);
        __syncthreads();  // staging visible to all waves

#pragma unroll
        for (int qf = 0; qf < 2; qf++) {
            const bf16x8 qa = qfrag[qf][0], qb2 = qfrag[qf][1];
#pragma unroll
            for (int kc2 = 0; kc2 < 4; kc2++) {
                f32x4 sc[2];
#pragma unroll
                for (int t = 0; t < 2; t++) {
                    const int krow = (kc2 * 2 + t) * 16 + m16;
                    f32x4 z = {};
                    z = mfma16(ld_bf8(&Ks[krow * DH + (quad ^ sA) * 8]), qa, z);
                    z = mfma16(ld_bf8(&Ks[krow * DH + ((quad + 4) ^ sA) * 8]), qb2, z);
                    sc[t] = z;
                }
                // alibi + exp2 + truncate-pack; lane holds keys kc+kc2*32+t*16+quad*4+r
#pragma unroll
                for (int t = 0; t < 2; t++) {
                    const float4 al = *(const float4*)(Apq[qf] + kc + kc2 * 32 + t * 16);
                    float p0 = fast_exp2(__builtin_fmaf(al.x, 1.44269504f, sc[t][0]));
                    float p1 = fast_exp2(__builtin_fmaf(al.y, 1.44269504f, sc[t][1]));
                    float p2 = fast_exp2(__builtin_fmaf(al.z, 1.44269504f, sc[t][2]));
                    float p3 = fast_exp2(__builtin_fmaf(al.w, 1.44269504f, sc[t][3]));
                    uint2 pk;
                    pk.x = (__builtin_bit_cast(unsigned, p0) >> 16) |
                           (__builtin_bit_cast(unsigned, p1) & 0xFFFF0000u);
                    pk.y = (__builtin_bit_cast(unsigned, p2) >> 16) |
                           (__builtin_bit_cast(unsigned, p3) & 0xFFFF0000u);
                    *(uint2*)&plw[m16 * 20 + t * 8 + quad * 2] = pk;
                }
                // P (A-layout) read-back; PV + ones-rowsum (same-wave DS ordering)
                const bf16x8 pf = ld_bf8((const unsigned short*)&plw[m16 * 20 + quad * 4]);
                ssum[qf] = mfma16(pf, onesf, ssum[qf]);
#pragma unroll
                for (int db = 0; db < 4; db++) {
                    const int vrow = db * 16 + m16;
                    const bf16x8 vf = ld_bf8(&Vs[vrow * 128 + ((kc2 * 4 + quad) ^ m16) * 8]);
                    oacc[qf][db] = mfma16(pf, vf, oacc[qf][db]);
                }
            }
        }
    }

    // normalize + store o as bf16 [B,S,D]; ssum rows == oacc rows (both C-layout)
#pragma unroll
    for (int qf = 0; qf < 2; qf++) {
        f32x4 rinv;
#pragma unroll
        for (int r = 0; r < 4; r++) rinv[r] = 1.0f / ssum[qf][r];
#pragma unroll
        for (int db = 0; db < 4; db++)
#pragma unroll
            for (int r = 0; r < 4; r++) {
                const int q = q0 + w * 32 + qf * 16 + quad * 4 + r;
                ob[((size_t)b_ * S_LEN + q) * DMODEL + hh * DH + db * 16 + m16] =
                    f2bf_rne(oacc[qf][db][r] * rinv[r]);
            }
    }
}

extern "C" void kernel_launch(void* const* d_in, const int* in_sizes, int n_in,
                              void* d_out, int out_size, void* d_ws, size_t ws_size,
                              hipStream_t stream) {
    (void)in_sizes; (void)n_in; (void)out_size; (void)ws_size;
    const float* x      = (const float*)d_in[0];
    const float* alibi  = (const float*)d_in[1];
    const float* w_qkv  = (const float*)d_in[2];
    const float* b_qkv  = (const float*)d_in[3];
    const float* w_o    = (const float*)d_in[4];
    const float* b_o    = (const float*)d_in[5];
    float* out = (float*)d_out;

    char* ws = (char*)d_ws;
    unsigned short* xb    = (unsigned short*)(ws);              // 16.78 MB
    unsigned short* wqkvb = (unsigned short*)(ws + 16777216);   //  6.29 MB
    unsigned short* wob   = (unsigned short*)(ws + 23068672);   //  2.10 MB
    unsigned short* Qb    = (unsigned short*)(ws + 25165824);   // 16.78 MB
    unsigned short* Kb    = (unsigned short*)(ws + 41943040);   // 16.78 MB
    unsigned short* Vt    = (unsigned short*)(ws + 58720256);   // 16.78 MB
    unsigned short* ob    = (unsigned short*)(ws + 75497472);   // 16.78 MB (total ~92 MB)

    cvt_bf16<<<8192, 256, 0, stream>>>(x, xb, 8388608 / 4);
    cvt_bf16<<<3072, 256, 0, stream>>>(w_qkv, wqkvb, 3145728 / 4);
    cvt_bf16<<<1024, 256, 0, stream>>>(w_o, wob, 1048576 / 4);

    gemm128<0><<<64 * 24, 256, 0, stream>>>(xb, wqkvb, b_qkv, nullptr, Qb, Kb, Vt, 24);
    attn<<<1024, 256, 0, stream>>>(Qb, Kb, Vt, alibi, ob);
    gemm128<1><<<64 * 8, 256, 0, stream>>>(ob, wob, b_o, out, nullptr, nullptr, nullptr, 8);
}